// Round 7
// baseline (502.987 us; speedup 1.0000x reference)
//
#include <hip/hip_runtime.h>
#include <math.h>

#define NBLK 128      // 128 workgroups x 1 wave x 2 batches = 256 batches
#define TT 4096
#define HH 32
#define CH 32         // steps per chunk (per-half x window = 32 lanes)

#if __has_builtin(__builtin_amdgcn_exp2f)
#define EXP2F(x) __builtin_amdgcn_exp2f(x)
#else
#define EXP2F(x) exp2f(x)
#endif

__device__ __forceinline__ float rlane(float v, int l) {
    return __uint_as_float(__builtin_amdgcn_readlane(__float_as_uint(v), l));
}

// TWO batches per wave: lanes 0-31 = batch A, lanes 32-63 = batch B.
// Lane hl = lane&31 computes output j = hl and carries rv = r[j]; every
// instruction advances both batches (pure SIMT). Full 32-term dot per lane:
//   phase 0 (up front): calibrated v_permlane16_swap gives rvO = r[hl^16]
//   phase 1: 16 v_fmac_f32_dpp row_ror:d on rv   -> own-row k-range
//   phase 2: 16 v_fmac_f32_dpp row_ror:d on rvO  -> other-row k-range
//            (swap latency hides under phase 1's fmacs)
// Tail has NO permlanes: dot complete per lane, rnw = r_new[j], rv = rnw.
// Iterate r = 1/(1+e^{2a}); h = 1-2r folded into weights/bias/W_fc.
// row_ror direction and permlane16_swap output are probed (R5/R6-verified).
__global__ __launch_bounds__(64, 1) void rnn_fused(
    const float* __restrict__ x,      // [B,T] (I==1)
    const float* __restrict__ W_ih,   // [H,1]
    const float* __restrict__ W_hh,   // [H,H]
    const float* __restrict__ b_ih,   // [H]
    const float* __restrict__ b_hh,   // [H]
    const float* __restrict__ W_fc,   // [1,H]
    const float* __restrict__ b_fc,   // [1]
    float* __restrict__ out)          // [B,T]
{
    const int lane = threadIdx.x;   // 0..63
    const int i16  = lane & 15;
    const int hl   = lane & 31;          // output index j within the batch
    const int half = lane >> 5;          // 0 = batch A, 1 = batch B
    const int row  = (hl >> 4) & 1;      // 16-lane row within the half
    const int j    = hl;

    __shared__ float obuf[64 * 65];   // r history: [lane][tc], stride 65

    const float KAPPA = 2.8853900817779268f;  // 2 * log2(e)

    // --- calibration probe 1: row_ror receive direction (R6-verified) ---
    int rr;
    asm volatile("s_nop 1\n\t"
                 "v_mov_b32_dpp %0, %1 row_ror:1 row_mask:0xf bank_mask:0xf"
                 : "=v"(rr) : "v"(lane));
    const int rsign = ((rr & 15) == ((i16 + 1) & 15)) ? 1 : -1;

    // --- calibration probe 2: which permlane16_swap output holds the
    //     OTHER row's value (rows swap pairwise 0<->1, 2<->3) ---
    int va = lane, vb = lane;
    asm volatile("s_nop 1\n\t"
                 "v_permlane16_swap_b32 %0, %1" : "+v"(va), "+v"(vb));
    const bool useA = (((va ^ lane) >> 4) & 1) != 0;

    float rowsum = 0.0f;
#pragma unroll
    for (int k = 0; k < HH; ++k) rowsum += W_hh[j * HH + k];

    // own-row k-base and other-row k-base for this lane
    const int ownb = row * 16;
    const int othb = 16 - ownb;

    // rotation-ordered weights: at row_ror:d this lane receives the value of
    // in-row lane (i16 + rsign*d)&15, which holds r[base + ((i16+rsign*d)&15)]
    float Wo[16], Wq[16];
#pragma unroll
    for (int d = 0; d < 16; ++d) {
        Wo[d] = -2.0f * KAPPA * W_hh[j * HH + ownb + ((i16 + rsign * d) & 15)];
        Wq[d] = -2.0f * KAPPA * W_hh[j * HH + othb + ((i16 + rsign * d) & 15)];
    }

    const float wih  = KAPPA * W_ih[j];
    const float bias = KAPPA * (b_ih[j] + b_hh[j] + rowsum);

    float wfcm[HH];
    float sum_wfc = 0.0f;
#pragma unroll
    for (int r = 0; r < HH; ++r) {
        float w = W_fc[r];
        sum_wfc += w;
        wfcm[r] = -2.0f * w;
    }
    const float bfc2 = b_fc[0] + sum_wfc;

    const size_t xb = ((size_t)blockIdx.x * 2 + half) * TT;  // per-half batch
    float xv = x[xb + hl];            // x window for chunk 0 (32 steps/half)
    float rv = 0.5f;                  // h=0 <=> r=0.5

    for (int c = 0; c < TT / CH; ++c) {
        const int cn = (c + 1) & (TT / CH - 1);      // wrapped prefetch
        float xv_next = x[xb + cn * CH + hl];

#pragma unroll 8
        for (int tc = 0; tc < CH; ++tc) {
            // per-half scalar input broadcast (off the critical chain)
            float sxA = rlane(xv, tc);
            float sxB = rlane(xv, 32 + tc);
            float sx  = half ? sxB : sxA;

            float acc0 = fmaf(wih, sx, bias);
            float acc1 = 0.0f, acc2 = 0.0f, acc3 = 0.0f;

            // other-row r values (swap latency hides under phase-1 fmacs)
            float fa = rv, fb = rv;
            asm("s_nop 1\n\t"
                "v_permlane16_swap_b32 %0, %1" : "+v"(fa), "+v"(fb));
            float rvO = useA ? fa : fb;

            // phase 1: own-row 16-term systolic partial
            asm("s_nop 1\n\t"
                "v_fmac_f32 %0, %4, %5\n\t"
                "v_fmac_f32_dpp %1, %4, %6 row_ror:1 row_mask:0xf bank_mask:0xf\n\t"
                "v_fmac_f32_dpp %2, %4, %7 row_ror:2 row_mask:0xf bank_mask:0xf\n\t"
                "v_fmac_f32_dpp %3, %4, %8 row_ror:3 row_mask:0xf bank_mask:0xf\n\t"
                "v_fmac_f32_dpp %0, %4, %9 row_ror:4 row_mask:0xf bank_mask:0xf\n\t"
                "v_fmac_f32_dpp %1, %4, %10 row_ror:5 row_mask:0xf bank_mask:0xf\n\t"
                "v_fmac_f32_dpp %2, %4, %11 row_ror:6 row_mask:0xf bank_mask:0xf\n\t"
                "v_fmac_f32_dpp %3, %4, %12 row_ror:7 row_mask:0xf bank_mask:0xf\n\t"
                "v_fmac_f32_dpp %0, %4, %13 row_ror:8 row_mask:0xf bank_mask:0xf\n\t"
                "v_fmac_f32_dpp %1, %4, %14 row_ror:9 row_mask:0xf bank_mask:0xf\n\t"
                "v_fmac_f32_dpp %2, %4, %15 row_ror:10 row_mask:0xf bank_mask:0xf\n\t"
                "v_fmac_f32_dpp %3, %4, %16 row_ror:11 row_mask:0xf bank_mask:0xf\n\t"
                "v_fmac_f32_dpp %0, %4, %17 row_ror:12 row_mask:0xf bank_mask:0xf\n\t"
                "v_fmac_f32_dpp %1, %4, %18 row_ror:13 row_mask:0xf bank_mask:0xf\n\t"
                "v_fmac_f32_dpp %2, %4, %19 row_ror:14 row_mask:0xf bank_mask:0xf\n\t"
                "v_fmac_f32_dpp %3, %4, %20 row_ror:15 row_mask:0xf bank_mask:0xf"
                : "+v"(acc0), "+v"(acc1), "+v"(acc2), "+v"(acc3)
                : "v"(rv),
                  "v"(Wo[0]),  "v"(Wo[1]),  "v"(Wo[2]),  "v"(Wo[3]),
                  "v"(Wo[4]),  "v"(Wo[5]),  "v"(Wo[6]),  "v"(Wo[7]),
                  "v"(Wo[8]),  "v"(Wo[9]),  "v"(Wo[10]), "v"(Wo[11]),
                  "v"(Wo[12]), "v"(Wo[13]), "v"(Wo[14]), "v"(Wo[15]));

            // phase 2: other-row 16-term systolic partial
            asm("v_fmac_f32 %0, %4, %5\n\t"
                "v_fmac_f32_dpp %1, %4, %6 row_ror:1 row_mask:0xf bank_mask:0xf\n\t"
                "v_fmac_f32_dpp %2, %4, %7 row_ror:2 row_mask:0xf bank_mask:0xf\n\t"
                "v_fmac_f32_dpp %3, %4, %8 row_ror:3 row_mask:0xf bank_mask:0xf\n\t"
                "v_fmac_f32_dpp %0, %4, %9 row_ror:4 row_mask:0xf bank_mask:0xf\n\t"
                "v_fmac_f32_dpp %1, %4, %10 row_ror:5 row_mask:0xf bank_mask:0xf\n\t"
                "v_fmac_f32_dpp %2, %4, %11 row_ror:6 row_mask:0xf bank_mask:0xf\n\t"
                "v_fmac_f32_dpp %3, %4, %12 row_ror:7 row_mask:0xf bank_mask:0xf\n\t"
                "v_fmac_f32_dpp %0, %4, %13 row_ror:8 row_mask:0xf bank_mask:0xf\n\t"
                "v_fmac_f32_dpp %1, %4, %14 row_ror:9 row_mask:0xf bank_mask:0xf\n\t"
                "v_fmac_f32_dpp %2, %4, %15 row_ror:10 row_mask:0xf bank_mask:0xf\n\t"
                "v_fmac_f32_dpp %3, %4, %16 row_ror:11 row_mask:0xf bank_mask:0xf\n\t"
                "v_fmac_f32_dpp %0, %4, %17 row_ror:12 row_mask:0xf bank_mask:0xf\n\t"
                "v_fmac_f32_dpp %1, %4, %18 row_ror:13 row_mask:0xf bank_mask:0xf\n\t"
                "v_fmac_f32_dpp %2, %4, %19 row_ror:14 row_mask:0xf bank_mask:0xf\n\t"
                "v_fmac_f32_dpp %3, %4, %20 row_ror:15 row_mask:0xf bank_mask:0xf"
                : "+v"(acc0), "+v"(acc1), "+v"(acc2), "+v"(acc3)
                : "v"(rvO),
                  "v"(Wq[0]),  "v"(Wq[1]),  "v"(Wq[2]),  "v"(Wq[3]),
                  "v"(Wq[4]),  "v"(Wq[5]),  "v"(Wq[6]),  "v"(Wq[7]),
                  "v"(Wq[8]),  "v"(Wq[9]),  "v"(Wq[10]), "v"(Wq[11]),
                  "v"(Wq[12]), "v"(Wq[13]), "v"(Wq[14]), "v"(Wq[15]));

            float p = (acc0 + acc1) + (acc2 + acc3);   // full preact * kappa

            float e   = EXP2F(p);
            float rnw = __builtin_amdgcn_rcpf(e + 1.0f);  // r in (0,1)

            rv = rnw;                       // lane j already holds r_new[j]
            obuf[lane * 65 + tc] = rnw;     // stash (DS pipe otherwise idle)
        }

        // epilogue: lane computes y for (batch=half, step t=hl):
        //   y = bfc2 + sum_j wfcm[j] * obuf[32*half + j][t]
        __builtin_amdgcn_wave_barrier();
        float s0 = 0.0f, s1 = 0.0f, s2 = 0.0f, s3 = 0.0f;
#pragma unroll
        for (int r = 0; r < HH; r += 4) {
            s0 = fmaf(obuf[(32 * half + r + 0) * 65 + hl], wfcm[r + 0], s0);
            s1 = fmaf(obuf[(32 * half + r + 1) * 65 + hl], wfcm[r + 1], s1);
            s2 = fmaf(obuf[(32 * half + r + 2) * 65 + hl], wfcm[r + 2], s2);
            s3 = fmaf(obuf[(32 * half + r + 3) * 65 + hl], wfcm[r + 3], s3);
        }
        out[xb + c * CH + hl] = (s0 + s1) + (s2 + s3) + bfc2;

        xv = xv_next;
        __builtin_amdgcn_wave_barrier();
    }
}

extern "C" void kernel_launch(void* const* d_in, const int* in_sizes, int n_in,
                              void* d_out, int out_size, void* d_ws, size_t ws_size,
                              hipStream_t stream) {
    const float* x    = (const float*)d_in[0];
    const float* W_ih = (const float*)d_in[1];
    const float* W_hh = (const float*)d_in[2];
    const float* b_ih = (const float*)d_in[3];
    const float* b_hh = (const float*)d_in[4];
    const float* W_fc = (const float*)d_in[5];
    const float* b_fc = (const float*)d_in[6];
    float* out = (float*)d_out;

    rnn_fused<<<NBLK, 64, 0, stream>>>(x, W_ih, W_hh, b_ih, b_hh, W_fc, b_fc, out);
}

// Round 11
// 352.109 us; speedup vs baseline: 1.4285x; 1.4285x over previous
//
#include <hip/hip_runtime.h>
#include <math.h>

#define NB 256
#define TT 4096
#define HH 32
#define CH 64   // timestep chunk: obuf columns, x-vector window

__device__ __forceinline__ float rlane(float v, int l) {
    return __uint_as_float(__builtin_amdgcn_readlane(__float_as_uint(v), l));
}

// One wave per batch; chain 100% VALU-pipe (R6 structure, PROVEN at 387us,
// rewritten as ONE fused asm block per step to kill compiler copy-movs,
// redundant s_nops, and block-boundary scheduling losses).
//   rows (16 lanes): row0=(out 0-15, kh=0), row1=(out 16-31, kh=1),
//                    row2=(out 0-15, kh=1), row3=(out 16-31, kh=0)
//   lane holds rv = r[kh*16+i16]; slot 1 fmac (seed in acc0), slots 2-4
//   v_mul_f32_dpp (init acc1-3, no zero-movs), 12 more fmac_dpp; tree;
//   permlane32_swap combine (sum direction-independent); exp2+rcp tail;
//   permlane16_swap + cndmask(SGPR-pair mask) layout fixup.
// Iterate r = 1/(1+e^{2a}); h = 1-2r folded into weights/bias/W_fc.
// Seed constants HALVED (combine sums both halves). Hazard spacing: every
// DPP/permlane read is >=2 slots from its producer; every trans (exp/rcp)
// consumer >=1 slot (movs/nops as spacers).
// HW unknowns (ror direction, permlane16 output order) probed in prologue.
__global__ __launch_bounds__(64, 1) void rnn_fused(
    const float* __restrict__ x,      // [B,T] (I==1)
    const float* __restrict__ W_ih,   // [H,1]
    const float* __restrict__ W_hh,   // [H,H]
    const float* __restrict__ b_ih,   // [H]
    const float* __restrict__ b_hh,   // [H]
    const float* __restrict__ W_fc,   // [1,H]
    const float* __restrict__ b_fc,   // [1]
    float* __restrict__ out)          // [B,T]
{
    const int lane = threadIdx.x;   // 0..63
    const int i16  = lane & 15;
    const int R    = lane >> 4;          // row 0..3
    const int j    = lane & 31;          // output index this lane computes
    const int kh   = (R ^ (R >> 1)) & 1; // K-half: rows 0,3 -> 0; 1,2 -> 1

    __shared__ float obuf[64 * 65];   // r history: [lane][tc], stride 65

    const float KAPPA = 2.8853900817779268f;  // 2 * log2(e)

    // --- probe 1: row_ror receive direction ---
    int rr;
    asm volatile("s_nop 1\n\t"
                 "v_mov_b32_dpp %0, %1 row_ror:1 row_mask:0xf bank_mask:0xf"
                 : "=v"(rr) : "v"(lane));
    const int rsign = ((rr & 15) == ((i16 + 1) & 15)) ? 1 : -1;

    // --- probe 2: which permlane16_swap output holds lane tgt's value ---
    int va = lane, vb = lane;
    asm volatile("s_nop 1\n\t"
                 "v_permlane16_swap_b32 %0, %1" : "+v"(va), "+v"(vb));
    const int  tgt  = kh * 16 + i16;      // lane whose r this lane needs
    const bool useA = ((va & 31) == tgt);
    const unsigned long long amask = __ballot(useA);  // cndmask SGPR mask

    float rowsum = 0.0f;
#pragma unroll
    for (int k = 0; k < HH; ++k) rowsum += W_hh[j * HH + k];

    // rotation-ordered weights: at row_ror:d this lane receives the value
    // of in-row lane (i16 + rsign*d)&15, which holds r[kh16 + that index]
    float Wo[16];
#pragma unroll
    for (int d = 0; d < 16; ++d)
        Wo[d] = -2.0f * KAPPA * W_hh[j * HH + kh * 16 + ((i16 + rsign * d) & 15)];

    // HALVED: the permlane32 combine sums this seed from both halves
    const float wihH  = 0.5f * KAPPA * W_ih[j];
    const float biasH = 0.5f * KAPPA * (b_ih[j] + b_hh[j] + rowsum);

    float wfcm[HH];
    float sum_wfc = 0.0f;
#pragma unroll
    for (int r = 0; r < HH; ++r) {
        float w = W_fc[r];
        sum_wfc += w;
        wfcm[r] = -2.0f * w;
    }
    const float bfc2 = b_fc[0] + sum_wfc;

    const size_t xbase = (size_t)blockIdx.x * TT;
    float xv = x[xbase + lane];
    float rv = 0.5f;                  // h=0 <=> r=0.5 (layout-independent)

    for (int c = 0; c < TT / CH; ++c) {
        const int cn = (c + 1) & (TT / CH - 1);      // wrapped prefetch
        float xv_next = x[xbase + cn * CH + lane];

#pragma unroll 8
        for (int tc = 0; tc < CH; ++tc) {
            float sx   = rlane(xv, tc);
            float acc0 = fmaf(wihH, sx, biasH);      // seed (off-chain)
            float acc1, acc2, acc3, sown, t1, t2;

            asm("v_fmac_f32 %0, %7, %10\n\t"
                "v_mul_f32_dpp %1, %7, %11 row_ror:1 row_mask:0xf bank_mask:0xf\n\t"
                "v_mul_f32_dpp %2, %7, %12 row_ror:2 row_mask:0xf bank_mask:0xf\n\t"
                "v_mul_f32_dpp %3, %7, %13 row_ror:3 row_mask:0xf bank_mask:0xf\n\t"
                "v_fmac_f32_dpp %0, %7, %14 row_ror:4 row_mask:0xf bank_mask:0xf\n\t"
                "v_fmac_f32_dpp %1, %7, %15 row_ror:5 row_mask:0xf bank_mask:0xf\n\t"
                "v_fmac_f32_dpp %2, %7, %16 row_ror:6 row_mask:0xf bank_mask:0xf\n\t"
                "v_fmac_f32_dpp %3, %7, %17 row_ror:7 row_mask:0xf bank_mask:0xf\n\t"
                "v_fmac_f32_dpp %0, %7, %18 row_ror:8 row_mask:0xf bank_mask:0xf\n\t"
                "v_fmac_f32_dpp %1, %7, %19 row_ror:9 row_mask:0xf bank_mask:0xf\n\t"
                "v_fmac_f32_dpp %2, %7, %20 row_ror:10 row_mask:0xf bank_mask:0xf\n\t"
                "v_fmac_f32_dpp %3, %7, %21 row_ror:11 row_mask:0xf bank_mask:0xf\n\t"
                "v_fmac_f32_dpp %0, %7, %22 row_ror:12 row_mask:0xf bank_mask:0xf\n\t"
                "v_fmac_f32_dpp %1, %7, %23 row_ror:13 row_mask:0xf bank_mask:0xf\n\t"
                "v_fmac_f32_dpp %2, %7, %24 row_ror:14 row_mask:0xf bank_mask:0xf\n\t"
                "v_fmac_f32_dpp %3, %7, %25 row_ror:15 row_mask:0xf bank_mask:0xf\n\t"
                "v_add_f32 %0, %0, %1\n\t"     // acc0+acc1
                "v_add_f32 %2, %2, %3\n\t"     // acc2+acc3
                "v_add_f32 %0, %0, %2\n\t"     // p
                "v_mov_b32 %5, %0\n\t"         // u = p   (spacer 1)
                "s_nop 0\n\t"                  //          (spacer 2)
                "v_permlane32_swap_b32 %0, %5\n\t"
                "v_add_f32 %0, %0, %5\n\t"     // dot = p + p[lane^32]
                "v_exp_f32 %0, %0\n\t"
                "s_nop 0\n\t"                  // trans wait
                "v_add_f32 %0, 1.0, %0\n\t"
                "v_rcp_f32 %4, %0\n\t"         // sown = r_new(j)
                "s_nop 0\n\t"                  // trans wait
                "v_mov_b32 %5, %4\n\t"         // t1 = sown
                "v_mov_b32 %6, %4\n\t"         // t2 = sown (spacer)
                "s_nop 0\n\t"
                "v_permlane16_swap_b32 %5, %6\n\t"
                "s_nop 0\n\t"
                "v_cndmask_b32 %7, %6, %5, %9" // rv = useA ? t1 : t2
                : "+v"(acc0), "=&v"(acc1), "=&v"(acc2), "=&v"(acc3),
                  "=&v"(sown), "=&v"(t1), "=&v"(t2), "+v"(rv)
                : "v"(acc0), "s"(amask),
                  "v"(Wo[0]),  "v"(Wo[1]),  "v"(Wo[2]),  "v"(Wo[3]),
                  "v"(Wo[4]),  "v"(Wo[5]),  "v"(Wo[6]),  "v"(Wo[7]),
                  "v"(Wo[8]),  "v"(Wo[9]),  "v"(Wo[10]), "v"(Wo[11]),
                  "v"(Wo[12]), "v"(Wo[13]), "v"(Wo[14]), "v"(Wo[15]));

            obuf[lane * 65 + tc] = sown;   // stash (off the chain)
        }

        // epilogue: lane t computes y_t = bfc2 + sum_j wfcm[j]*r_t[j]
        __builtin_amdgcn_wave_barrier();
        float s0 = 0.0f, s1 = 0.0f, s2 = 0.0f, s3 = 0.0f;
#pragma unroll
        for (int r = 0; r < HH; r += 4) {
            s0 = fmaf(obuf[(r + 0) * 65 + lane], wfcm[r + 0], s0);
            s1 = fmaf(obuf[(r + 1) * 65 + lane], wfcm[r + 1], s1);
            s2 = fmaf(obuf[(r + 2) * 65 + lane], wfcm[r + 2], s2);
            s3 = fmaf(obuf[(r + 3) * 65 + lane], wfcm[r + 3], s3);
        }
        out[xbase + c * CH + lane] = (s0 + s1) + (s2 + s3) + bfc2;

        xv = xv_next;
        __builtin_amdgcn_wave_barrier();
    }
}

extern "C" void kernel_launch(void* const* d_in, const int* in_sizes, int n_in,
                              void* d_out, int out_size, void* d_ws, size_t ws_size,
                              hipStream_t stream) {
    const float* x    = (const float*)d_in[0];
    const float* W_ih = (const float*)d_in[1];
    const float* W_hh = (const float*)d_in[2];
    const float* b_ih = (const float*)d_in[3];
    const float* b_hh = (const float*)d_in[4];
    const float* W_fc = (const float*)d_in[5];
    const float* b_fc = (const float*)d_in[6];
    float* out = (float*)d_out;

    rnn_fused<<<NB, 64, 0, stream>>>(x, W_ih, W_hh, b_ih, b_hh, W_fc, b_fc, out);
}

// Round 12
// 329.962 us; speedup vs baseline: 1.5244x; 1.0671x over previous
//
#include <hip/hip_runtime.h>
#include <math.h>

#define NB 256
#define TT 4096
#define HH 32
#define CH 64   // timestep chunk: obuf columns

// One wave per batch; recurrent chain 100% VALU-pipe. Layout (R6/R11 proven):
//   rows (16 lanes): row0=(out 0-15, kh=0), row1=(out 16-31, kh=1),
//                    row2=(out 0-15, kh=1), row3=(out 16-31, kh=0)
//   lane holds rv = r[kh*16+i16]; 16 fmac(+DPP ror) accumulate the 16-term
//   partial into 2 accs; permlane32_swap combine (sum = direction-free).
// NEW vs R11: the row2/3 layout fixup is applied to the DOT (pre-exp) via
// permlane16_swap + cndmask, so rcp writes the needed state DIRECTLY into
// rv (no post-rcp fixup). obuf keeps own-r for lanes 0-31 (epilogue only
// reads rows 0-31; upper-lane writes are dead). x is loaded with uniform
// indices -> scalar s_load (SALU pipe), killing the readlane.
// Iterate r = 1/(1+e^{2a}); h = 1-2r folded into weights/bias/W_fc.
// Seed constants HALVED (combine sums both halves' seeds).
__global__ __launch_bounds__(64, 1) void rnn_fused(
    const float* __restrict__ x,      // [B,T] (I==1)
    const float* __restrict__ W_ih,   // [H,1]
    const float* __restrict__ W_hh,   // [H,H]
    const float* __restrict__ b_ih,   // [H]
    const float* __restrict__ b_hh,   // [H]
    const float* __restrict__ W_fc,   // [1,H]
    const float* __restrict__ b_fc,   // [1]
    float* __restrict__ out)          // [B,T]
{
    const int lane = threadIdx.x;   // 0..63
    const int i16  = lane & 15;
    const int R    = lane >> 4;          // row 0..3
    const int j    = lane & 31;          // output index this lane computes
    const int kh   = (R ^ (R >> 1)) & 1; // K-half: rows 0,3 -> 0; 1,2 -> 1

    __shared__ float obuf[64 * 65];   // r history: [lane][tc], stride 65

    const float KAPPA = 2.8853900817779268f;  // 2 * log2(e)

    // --- probe 1: row_ror receive direction ---
    int rr;
    asm volatile("s_nop 1\n\t"
                 "v_mov_b32_dpp %0, %1 row_ror:1 row_mask:0xf bank_mask:0xf"
                 : "=v"(rr) : "v"(lane));
    const int rsign = ((rr & 15) == ((i16 + 1) & 15)) ? 1 : -1;

    // --- probe 2: permlane16_swap output mapping for the DOT fixup.
    // Lane needs dot[needIdx]: lanes 0-31 own dot; rows 2,3 partner row's.
    int va = lane, vb = lane;
    asm volatile("s_nop 1\n\t"
                 "v_permlane16_swap_b32 %0, %1" : "+v"(va), "+v"(vb));
    const int needIdx = (lane < 32) ? lane : (lane ^ 16);
    const unsigned long long maskD = __ballot(va == needIdx);

    float rowsum = 0.0f;
#pragma unroll
    for (int k = 0; k < HH; ++k) rowsum += W_hh[j * HH + k];

    // rotation-ordered weights: at row_ror:d this lane receives the value
    // of in-row lane (i16 + rsign*d)&15, which holds r[kh16 + that index]
    float Wo[16];
#pragma unroll
    for (int d = 0; d < 16; ++d)
        Wo[d] = -2.0f * KAPPA * W_hh[j * HH + kh * 16 + ((i16 + rsign * d) & 15)];

    // HALVED: the permlane32 combine sums this seed from both halves
    const float wihH  = 0.5f * KAPPA * W_ih[j];
    const float biasH = 0.5f * KAPPA * (b_ih[j] + b_hh[j] + rowsum);

    float wfcm[HH];
    float sum_wfc = 0.0f;
#pragma unroll
    for (int r = 0; r < HH; ++r) {
        float w = W_fc[r];
        sum_wfc += w;
        wfcm[r] = -2.0f * w;
    }
    const float bfc2 = b_fc[0] + sum_wfc;

    const size_t xbase = (size_t)blockIdx.x * TT;
    float rv = 0.5f;                  // h=0 <=> r=0.5 (layout-independent)

    for (int c = 0; c < TT / CH; ++c) {
        const float* xc = x + xbase + (size_t)c * CH;   // uniform base

#pragma unroll 8
        for (int tc = 0; tc < CH; ++tc) {
            // r_{tc-1} history write (also fills the rcp->DPP hazard window)
            if (tc > 0) obuf[lane * 65 + (tc - 1)] = rv;

            // uniform x -> scalar load (SALU); seed fma (plain VALU)
            float accC = fmaf(wihH, xc[tc], biasH);
            float acc1, t, td;

            asm("v_fmac_f32 %0, %2, %5\n\t"
                "v_mul_f32_dpp %1, %2, %6 row_ror:1 row_mask:0xf bank_mask:0xf\n\t"
                "v_fmac_f32_dpp %0, %2, %7 row_ror:2 row_mask:0xf bank_mask:0xf\n\t"
                "v_fmac_f32_dpp %1, %2, %8 row_ror:3 row_mask:0xf bank_mask:0xf\n\t"
                "v_fmac_f32_dpp %0, %2, %9 row_ror:4 row_mask:0xf bank_mask:0xf\n\t"
                "v_fmac_f32_dpp %1, %2, %10 row_ror:5 row_mask:0xf bank_mask:0xf\n\t"
                "v_fmac_f32_dpp %0, %2, %11 row_ror:6 row_mask:0xf bank_mask:0xf\n\t"
                "v_fmac_f32_dpp %1, %2, %12 row_ror:7 row_mask:0xf bank_mask:0xf\n\t"
                "v_fmac_f32_dpp %0, %2, %13 row_ror:8 row_mask:0xf bank_mask:0xf\n\t"
                "v_fmac_f32_dpp %1, %2, %14 row_ror:9 row_mask:0xf bank_mask:0xf\n\t"
                "v_fmac_f32_dpp %0, %2, %15 row_ror:10 row_mask:0xf bank_mask:0xf\n\t"
                "v_fmac_f32_dpp %1, %2, %16 row_ror:11 row_mask:0xf bank_mask:0xf\n\t"
                "v_fmac_f32_dpp %0, %2, %17 row_ror:12 row_mask:0xf bank_mask:0xf\n\t"
                "v_fmac_f32_dpp %1, %2, %18 row_ror:13 row_mask:0xf bank_mask:0xf\n\t"
                "v_fmac_f32_dpp %0, %2, %19 row_ror:14 row_mask:0xf bank_mask:0xf\n\t"
                "v_fmac_f32_dpp %1, %2, %20 row_ror:15 row_mask:0xf bank_mask:0xf\n\t"
                "v_add_f32 %0, %0, %1\n\t"     // p
                "v_mov_b32 %3, %0\n\t"         // t = p
                "s_nop 0\n\t"
                "v_permlane32_swap_b32 %0, %3\n\t"
                "v_add_f32 %0, %0, %3\n\t"     // d = p + p[lane^32]
                "v_mov_b32 %4, %0\n\t"         // td = d
                "s_nop 0\n\t"
                "v_permlane16_swap_b32 %4, %0\n\t"
                "s_nop 0\n\t"
                "v_cndmask_b32 %0, %0, %4, %21\n\t"  // d_sel = needed dot
                "v_exp_f32 %0, %0\n\t"
                "s_nop 0\n\t"
                "v_add_f32 %0, 1.0, %0\n\t"
                "v_rcp_f32 %2, %0"             // rv = needed r DIRECTLY
                : "+v"(accC), "=&v"(acc1), "+v"(rv), "=&v"(t), "=&v"(td)
                : "v"(Wo[0]),  "v"(Wo[1]),  "v"(Wo[2]),  "v"(Wo[3]),
                  "v"(Wo[4]),  "v"(Wo[5]),  "v"(Wo[6]),  "v"(Wo[7]),
                  "v"(Wo[8]),  "v"(Wo[9]),  "v"(Wo[10]), "v"(Wo[11]),
                  "v"(Wo[12]), "v"(Wo[13]), "v"(Wo[14]), "v"(Wo[15]),
                  "s"(maskD));
        }
        obuf[lane * 65 + 63] = rv;    // last step's state for this chunk

        // epilogue: lane t computes y_t = bfc2 + sum_j wfcm[j]*r_t[j]
        __builtin_amdgcn_wave_barrier();
        float s0 = 0.0f, s1 = 0.0f, s2 = 0.0f, s3 = 0.0f;
#pragma unroll
        for (int r = 0; r < HH; r += 4) {
            s0 = fmaf(obuf[(r + 0) * 65 + lane], wfcm[r + 0], s0);
            s1 = fmaf(obuf[(r + 1) * 65 + lane], wfcm[r + 1], s1);
            s2 = fmaf(obuf[(r + 2) * 65 + lane], wfcm[r + 2], s2);
            s3 = fmaf(obuf[(r + 3) * 65 + lane], wfcm[r + 3], s3);
        }
        out[xbase + c * CH + lane] = (s0 + s1) + (s2 + s3) + bfc2;

        __builtin_amdgcn_wave_barrier();
    }
}

extern "C" void kernel_launch(void* const* d_in, const int* in_sizes, int n_in,
                              void* d_out, int out_size, void* d_ws, size_t ws_size,
                              hipStream_t stream) {
    const float* x    = (const float*)d_in[0];
    const float* W_ih = (const float*)d_in[1];
    const float* W_hh = (const float*)d_in[2];
    const float* b_ih = (const float*)d_in[3];
    const float* b_hh = (const float*)d_in[4];
    const float* W_fc = (const float*)d_in[5];
    const float* b_fc = (const float*)d_in[6];
    float* out = (float*)d_out;

    rnn_fused<<<NB, 64, 0, stream>>>(x, W_ih, W_hh, b_ih, b_hh, W_fc, b_fc, out);
}

// Round 14
// 321.137 us; speedup vs baseline: 1.5663x; 1.0275x over previous
//
#include <hip/hip_runtime.h>
#include <math.h>

#define NB 256
#define TT 4096
#define HH 32
#define CH 64   // timestep chunk: obuf columns

// One wave per batch; recurrent chain 100% VALU-pipe. Layout (R6-R12 proven):
//   rows (16 lanes): row0=(out 0-15, kh=0), row1=(out 16-31, kh=1),
//                    row2=(out 0-15, kh=1), row3=(out 16-31, kh=0)
//   lane holds rv = r[kh*16+i16]; seed fma + 16 fmac(+DPP ror) accumulate
//   into 2 acc chains; permlane32_swap combine (sum = direction-free);
//   pre-exp permlane16_swap+cndmask hands rows 2,3 their partner dot, so
//   exp->rcp lands the needed state DIRECTLY in rv.
// R13 LESSON (absmax 1.17e6): gfx950 REQUIRES >=1 wait state between a VALU
// write and a permlane read of it, and >=1 after trans (exp/rcp) before a
// dependent VALU read. R12's 3-4 s_nop positions are HW-mandated minimums
// and are preserved exactly here.
// R14: fold ALL per-step work into the one asm block at fixed spacing:
// seed fma inside (x as SGPR operand), acc1 init via mul, no copy-movs.
// Iterate r = 1/(1+e^{2a}); h = 1-2r folded into weights/bias/W_fc.
// Seed constants HALVED (combine sums both halves' seeds).
__global__ __launch_bounds__(64, 1) void rnn_fused(
    const float* __restrict__ x,      // [B,T] (I==1)
    const float* __restrict__ W_ih,   // [H,1]
    const float* __restrict__ W_hh,   // [H,H]
    const float* __restrict__ b_ih,   // [H]
    const float* __restrict__ b_hh,   // [H]
    const float* __restrict__ W_fc,   // [1,H]
    const float* __restrict__ b_fc,   // [1]
    float* __restrict__ out)          // [B,T]
{
    const int lane = threadIdx.x;   // 0..63
    const int i16  = lane & 15;
    const int R    = lane >> 4;          // row 0..3
    const int j    = lane & 31;          // output index this lane computes
    const int kh   = (R ^ (R >> 1)) & 1; // K-half: rows 0,3 -> 0; 1,2 -> 1

    __shared__ float obuf[64 * 65];   // r history: [lane][tc], stride 65

    const float KAPPA = 2.8853900817779268f;  // 2 * log2(e)

    // --- probe 1: row_ror receive direction ---
    int rr;
    asm volatile("s_nop 1\n\t"
                 "v_mov_b32_dpp %0, %1 row_ror:1 row_mask:0xf bank_mask:0xf"
                 : "=v"(rr) : "v"(lane));
    const int rsign = ((rr & 15) == ((i16 + 1) & 15)) ? 1 : -1;

    // --- probe 2: permlane16_swap output mapping for the DOT fixup.
    // Lane needs dot[needIdx]: lanes 0-31 own dot; rows 2,3 partner row's.
    int va = lane, vb = lane;
    asm volatile("s_nop 1\n\t"
                 "v_permlane16_swap_b32 %0, %1" : "+v"(va), "+v"(vb));
    const int needIdx = (lane < 32) ? lane : (lane ^ 16);
    const unsigned long long maskD = __ballot(va == needIdx);

    float rowsum = 0.0f;
#pragma unroll
    for (int k = 0; k < HH; ++k) rowsum += W_hh[j * HH + k];

    // rotation-ordered weights: at row_ror:d this lane receives the value
    // of in-row lane (i16 + rsign*d)&15, which holds r[kh16 + that index]
    float Wo[16];
#pragma unroll
    for (int d = 0; d < 16; ++d)
        Wo[d] = -2.0f * KAPPA * W_hh[j * HH + kh * 16 + ((i16 + rsign * d) & 15)];

    // HALVED: the permlane32 combine sums this seed from both halves
    const float wihH  = 0.5f * KAPPA * W_ih[j];
    const float biasH = 0.5f * KAPPA * (b_ih[j] + b_hh[j] + rowsum);

    float wfcm[HH];
    float sum_wfc = 0.0f;
#pragma unroll
    for (int r = 0; r < HH; ++r) {
        float w = W_fc[r];
        sum_wfc += w;
        wfcm[r] = -2.0f * w;
    }
    const float bfc2 = b_fc[0] + sum_wfc;

    const size_t xbase = (size_t)blockIdx.x * TT;
    float rv = 0.5f;                  // h=0 <=> r=0.5 (layout-independent)

    for (int c = 0; c < TT / CH; ++c) {
        const float* xc = x + xbase + (size_t)c * CH;   // uniform base

#pragma unroll 8
        for (int tc = 0; tc < CH; ++tc) {
            // r_{tc-1} history write (independent; fills inter-block gap)
            if (tc > 0) obuf[lane * 65 + (tc - 1)] = rv;

            float acc0, acc1, t, td;

            asm("v_fma_f32 %0, %5, %22, %6\n\t"   // seed: wih*x + bias
                "v_mul_f32_dpp %1, %2, %8 row_ror:1 row_mask:0xf bank_mask:0xf\n\t"
                "v_fmac_f32 %0, %2, %7\n\t"        // ror:0 term
                "v_fmac_f32_dpp %1, %2, %10 row_ror:3 row_mask:0xf bank_mask:0xf\n\t"
                "v_fmac_f32_dpp %0, %2, %9 row_ror:2 row_mask:0xf bank_mask:0xf\n\t"
                "v_fmac_f32_dpp %1, %2, %12 row_ror:5 row_mask:0xf bank_mask:0xf\n\t"
                "v_fmac_f32_dpp %0, %2, %11 row_ror:4 row_mask:0xf bank_mask:0xf\n\t"
                "v_fmac_f32_dpp %1, %2, %14 row_ror:7 row_mask:0xf bank_mask:0xf\n\t"
                "v_fmac_f32_dpp %0, %2, %13 row_ror:6 row_mask:0xf bank_mask:0xf\n\t"
                "v_fmac_f32_dpp %1, %2, %16 row_ror:9 row_mask:0xf bank_mask:0xf\n\t"
                "v_fmac_f32_dpp %0, %2, %15 row_ror:8 row_mask:0xf bank_mask:0xf\n\t"
                "v_fmac_f32_dpp %1, %2, %18 row_ror:11 row_mask:0xf bank_mask:0xf\n\t"
                "v_fmac_f32_dpp %0, %2, %17 row_ror:10 row_mask:0xf bank_mask:0xf\n\t"
                "v_fmac_f32_dpp %1, %2, %20 row_ror:13 row_mask:0xf bank_mask:0xf\n\t"
                "v_fmac_f32_dpp %0, %2, %19 row_ror:12 row_mask:0xf bank_mask:0xf\n\t"
                "v_fmac_f32_dpp %1, %2, %21 row_ror:15 row_mask:0xf bank_mask:0xf\n\t"
                "v_fmac_f32_dpp %0, %2, %23 row_ror:14 row_mask:0xf bank_mask:0xf\n\t"
                "v_add_f32 %3, %0, %1\n\t"     // t = p
                "v_add_f32 %0, %0, %1\n\t"     // p
                "s_nop 0\n\t"                  // HW wait: VALU->permlane
                "v_permlane32_swap_b32 %0, %3\n\t"
                "v_add_f32 %1, %0, %3\n\t"     // d
                "v_add_f32 %4, %0, %3\n\t"     // td = d
                "s_nop 0\n\t"                  // HW wait: VALU->permlane
                "v_permlane16_swap_b32 %4, %1\n\t"
                "s_nop 0\n\t"                  // HW wait: permlane->VALU
                "v_cndmask_b32 %1, %1, %4, %24\n\t"  // d_sel = needed dot
                "v_exp_f32 %1, %1\n\t"
                "s_nop 0\n\t"                  // HW wait: trans->VALU
                "v_add_f32 %1, 1.0, %1\n\t"
                "v_rcp_f32 %2, %1"             // rv = needed r DIRECTLY
                : "=&v"(acc0), "=&v"(acc1), "+v"(rv), "=&v"(t), "=&v"(td)
                : "v"(wihH), "v"(biasH),
                  "v"(Wo[0]),  "v"(Wo[1]),  "v"(Wo[2]),  "v"(Wo[3]),
                  "v"(Wo[4]),  "v"(Wo[5]),  "v"(Wo[6]),  "v"(Wo[7]),
                  "v"(Wo[8]),  "v"(Wo[9]),  "v"(Wo[10]), "v"(Wo[11]),
                  "v"(Wo[12]), "v"(Wo[13]), "v"(Wo[15]),
                  "s"(xc[tc]), "v"(Wo[14]), "s"(maskD));
        }
        obuf[lane * 65 + 63] = rv;    // last step's state for this chunk

        // epilogue: lane t computes y_t = bfc2 + sum_j wfcm[j]*r_t[j]
        __builtin_amdgcn_wave_barrier();
        float s0 = 0.0f, s1 = 0.0f, s2 = 0.0f, s3 = 0.0f;
#pragma unroll
        for (int r = 0; r < HH; r += 4) {
            s0 = fmaf(obuf[(r + 0) * 65 + lane], wfcm[r + 0], s0);
            s1 = fmaf(obuf[(r + 1) * 65 + lane], wfcm[r + 1], s1);
            s2 = fmaf(obuf[(r + 2) * 65 + lane], wfcm[r + 2], s2);
            s3 = fmaf(obuf[(r + 3) * 65 + lane], wfcm[r + 3], s3);
        }
        out[xbase + c * CH + lane] = (s0 + s1) + (s2 + s3) + bfc2;

        __builtin_amdgcn_wave_barrier();
    }
}

extern "C" void kernel_launch(void* const* d_in, const int* in_sizes, int n_in,
                              void* d_out, int out_size, void* d_ws, size_t ws_size,
                              hipStream_t stream) {
    const float* x    = (const float*)d_in[0];
    const float* W_ih = (const float*)d_in[1];
    const float* W_hh = (const float*)d_in[2];
    const float* b_ih = (const float*)d_in[3];
    const float* b_hh = (const float*)d_in[4];
    const float* W_fc = (const float*)d_in[5];
    const float* b_fc = (const float*)d_in[6];
    float* out = (float*)d_out;

    rnn_fused<<<NB, 64, 0, stream>>>(x, W_ih, W_hh, b_ih, b_hh, W_fc, b_fc, out);
}